// Round 1
// baseline (344.084 us; speedup 1.0000x reference)
//
#include <hip/hip_runtime.h>

// DifferentiableTMO: per-batch piecewise-linear CRF LUT applied to 8x3x1080x1920 fp32.
// HBM-bound: 199MB in + 199MB out -> ~63us floor @6.3TB/s.

#define KS 256          // CRF sample points
#define NB 25           // PCA basis curves
#define M_BINS 4096     // bucket-accel bins over [0,1)
#define BINS_PER_THR (M_BINS / 256)
#define NPIX_PER_B 6220800   // 3*1080*1920
#define NP4 (NPIX_PER_B / 4) // 1555200, exact

__device__ __forceinline__ float interp_one(float x,
                                            const float* __restrict__ sE,
                                            const float4* __restrict__ sT,
                                            const unsigned short* __restrict__ sBkt)
{
    // x in [0,1): m = floor(x*4096) exactly (mul by 2^12 is an exponent shift, no rounding)
    int m = (int)(x * 4096.0f);
    m = (m > M_BINS - 1) ? (M_BINS - 1) : m;   // safety for x >= 1 (shouldn't occur)
    int j = sBkt[m];                            // j = upper_bound(E, m/4096) <= upper_bound(E, x)
    while (j < KS && sE[j] <= x) ++j;           // short scan: ~1/16 E-points per bin
    float4 t = sT[j];                           // (E[j-1], curve[j-1], slope, -)
    float y = fmaf(t.z, x - t.x, t.y);          // exact np.interp form
    return fminf(fmaxf(y, 0.0f), 1.0f);         // clip(0,1)
}

__global__ __launch_bounds__(256, 8)
void tmo_lut_kernel(const float* __restrict__ hdr,
                    const float* __restrict__ w,
                    const float* __restrict__ E,
                    const float* __restrict__ f0,
                    const float* __restrict__ Hb,
                    float* __restrict__ out)
{
    __shared__ float sE[KS];
    __shared__ float sC[KS];
    __shared__ float4 sT[KS + 1];
    __shared__ unsigned short sBkt[M_BINS];

    const int tid = threadIdx.x;
    const int b   = blockIdx.y;

    // ---- stage E, build per-batch curve: curve[k] = f0[k] + sum_n Hb[k,n]*w[b,n] ----
    sE[tid] = E[tid];
    {
        float acc = f0[tid];
        const float* wb = w + b * NB;       // block-uniform -> scalar loads
        const float* hb = Hb + tid * NB;
        #pragma unroll
        for (int n = 0; n < NB; ++n) acc = fmaf(hb[n], wb[n], acc);
        sC[tid] = acc;
    }
    __syncthreads();

    // ---- segment table sT[j] for j = upper_bound(E,x) in [0,256] ----
    if (tid == 0) {
        sT[0]  = make_float4(sE[0],      sC[0],      0.0f, 0.0f);  // x < E[0]  -> curve[0]
        sT[KS] = make_float4(sE[KS - 1], sC[KS - 1], 0.0f, 0.0f);  // x >= E[K-1] -> curve[K-1]
    } else {
        float e0 = sE[tid - 1], e1 = sE[tid];
        float c0 = sC[tid - 1], c1 = sC[tid];
        float sl = (c1 - c0) / (e1 - e0);
        sT[tid] = make_float4(e0, c0, sl, 0.0f);
    }

    // ---- bucket LUT: sBkt[m] = upper_bound(E, m/4096); 16 bins/thread via search+merge ----
    {
        const float invM = 1.0f / (float)M_BINS;   // m*invM exact (m < 2^12)
        int m0 = tid * BINS_PER_THR;
        float v0 = (float)m0 * invM;
        int lo = 0, hi = KS;
        while (lo < hi) {                 // binary search for first bin
            int mid = (lo + hi) >> 1;
            if (sE[mid] <= v0) lo = mid + 1; else hi = mid;
        }
        int j = lo;
        for (int m = m0; m < m0 + BINS_PER_THR; ++m) {
            float mv = (float)m * invM;
            while (j < KS && sE[j] <= mv) ++j;
            sBkt[m] = (unsigned short)j;
        }
    }
    __syncthreads();

    // ---- main streaming loop: one batch per block row, float4 in/out ----
    const float4* in4  = (const float4*)(hdr + (size_t)b * NPIX_PER_B);
    float4*       out4 = (float4*)(out + (size_t)b * NPIX_PER_B);

    const int stride = gridDim.x * blockDim.x;
    for (int i = blockIdx.x * blockDim.x + tid; i < NP4; i += stride) {
        float4 p = in4[i];
        float4 r;
        r.x = interp_one(p.x, sE, sT, sBkt);
        r.y = interp_one(p.y, sE, sT, sBkt);
        r.z = interp_one(p.z, sE, sT, sBkt);
        r.w = interp_one(p.w, sE, sT, sBkt);
        out4[i] = r;
    }
}

extern "C" void kernel_launch(void* const* d_in, const int* in_sizes, int n_in,
                              void* d_out, int out_size, void* d_ws, size_t ws_size,
                              hipStream_t stream)
{
    const float* hdr = (const float*)d_in[0];  // [8,3,1080,1920]
    const float* w   = (const float*)d_in[1];  // [8,25]
    const float* E   = (const float*)d_in[2];  // [256] sorted
    const float* f0  = (const float*)d_in[3];  // [256]
    const float* Hb  = (const float*)d_in[4];  // [256,25]
    float* out = (float*)d_out;

    dim3 grid(256, 8, 1);   // 2048 blocks = 8 blocks/CU * 256 CUs, 32 waves/CU
    dim3 block(256, 1, 1);
    tmo_lut_kernel<<<grid, block, 0, stream>>>(hdr, w, E, f0, Hb, out);
}

// Round 3
// 337.416 us; speedup vs baseline: 1.0198x; 1.0198x over previous
//
#include <hip/hip_runtime.h>

// DifferentiableTMO: per-batch piecewise-linear CRF LUT over 8x3x1080x1920 fp32.
// HBM floor: 199MB read + 199MB write ~= 63us @6.3TB/s.
// R2: fix nontemporal store (needs native clang vector type, not HIP_vector_type).
//     Scan-free bucket (j|count packed), (slope,intercept) b64 segments, U=4 loads.

#define KS 256          // CRF sample points
#define NB 25           // PCA basis curves
#define M_BINS 4096     // bucket bins over [0,1)
#define BINS_PER_THR (M_BINS / 256)   // 16
#define NPIX_PER_B 6220800            // 3*1080*1920
#define NP4 (NPIX_PER_B / 4)          // 1555200 float4 per batch

typedef float nvec4 __attribute__((ext_vector_type(4)));   // native vector for nt-store

__device__ __forceinline__ void nt_store4(float4* dst, float4 v)
{
    __builtin_nontemporal_store(*(const nvec4*)&v, (nvec4*)dst);
}

__device__ __forceinline__ float interp_one(float x,
                                            const float* __restrict__ sE,
                                            const float2* __restrict__ sSeg,
                                            const unsigned short* __restrict__ sBkt)
{
    // x in [0,1): m = floor(x*4096) exact (x*2^12 is an exponent shift)
    int m = (int)(x * (float)M_BINS);
    m = (m > M_BINS - 1) ? (M_BINS - 1) : m;
    unsigned int pk = sBkt[m];
    unsigned int j  = pk & 0x1FFu;     // upper_bound(E, m/4096)
    unsigned int c  = pk >> 9;         // # breakpoints inside this bin (0 for ~94%)
    while (c) {                        // only lanes in breakpoint bins issue LDS here
        if (sE[j] > x) break;
        ++j; --c;
    }
    float2 sg = sSeg[j];               // (slope, intercept), ds_read_b64
    float y = fmaf(sg.x, x, sg.y);
    return fminf(fmaxf(y, 0.0f), 1.0f);
}

__global__ __launch_bounds__(256, 8)
void tmo_lut_kernel(const float* __restrict__ hdr,
                    const float* __restrict__ w,
                    const float* __restrict__ E,
                    const float* __restrict__ f0,
                    const float* __restrict__ Hb,
                    float* __restrict__ out)
{
    __shared__ float  sE[KS];
    __shared__ float  sC[KS];
    __shared__ float2 sSeg[KS + 1];               // (slope, intercept) by upper_bound index
    __shared__ unsigned short sBkt[M_BINS];       // j | (count<<9)

    const int tid = threadIdx.x;
    const int b   = blockIdx.y;

    // ---- stage E, per-batch curve: curve[k] = f0[k] + sum_n Hb[k,n]*w[b,n] ----
    sE[tid] = E[tid];
    {
        float acc = f0[tid];
        const float* wb = w + b * NB;   // block-uniform -> scalar loads
        const float* hb = Hb + tid * NB;
        #pragma unroll
        for (int n = 0; n < NB; ++n) acc = fmaf(hb[n], wb[n], acc);
        sC[tid] = acc;
    }
    __syncthreads();

    // ---- segment table: for j = upper_bound(E,x), y = slope*x + intercept ----
    if (tid == 0) {
        sSeg[0]  = make_float2(0.0f, sC[0]);       // x < E[0]    -> curve[0]
        sSeg[KS] = make_float2(0.0f, sC[KS - 1]);  // x >= E[K-1] -> curve[K-1]
    } else {
        float e0 = sE[tid - 1], e1 = sE[tid];
        float c0 = sC[tid - 1], c1 = sC[tid];
        float sl = (c1 - c0) / (e1 - e0);
        float bi = fmaf(-sl, e0, c0);              // intercept = c0 - sl*e0
        sSeg[tid] = make_float2(sl, bi);
    }

    // ---- bucket LUT: sBkt[m] = upper_bound(E, m/4096) | count<<9 ----
    {
        const float h = 1.0f / (float)M_BINS;      // m*h exact for m < 2^12
        int m0 = tid * BINS_PER_THR;
        float v0 = (float)m0 * h;
        int lo = 0, hi = KS;
        while (lo < hi) {                          // binary search: first E > v0
            int mid = (lo + hi) >> 1;
            if (sE[mid] <= v0) lo = mid + 1; else hi = mid;
        }
        int j = lo;
        for (int t = 0; t < BINS_PER_THR; ++t) {
            int m = m0 + t;
            float vn = (float)(m + 1) * h;
            int jn = j;
            while (jn < KS && sE[jn] <= vn) ++jn;  // first E > (m+1)/4096
            int c = jn - j;                        // breakpoints in bin
            c = (c > 127) ? 127 : c;
            sBkt[m] = (unsigned short)(j | (c << 9));
            j = jn;
        }
    }
    __syncthreads();

    // ---- streaming loop: one batch per blockIdx.y, float4 in/out, U=4 MLP ----
    const float4* __restrict__ in4 = (const float4*)(hdr + (size_t)b * NPIX_PER_B);
    float4*                   out4 = (float4*)(out + (size_t)b * NPIX_PER_B);

    const int stride = gridDim.x * blockDim.x;     // 65536
    int i = blockIdx.x * blockDim.x + tid;

    for (; i + 3 * stride < NP4; i += 4 * stride) {
        float4 p0 = in4[i];
        float4 p1 = in4[i +     stride];
        float4 p2 = in4[i + 2 * stride];
        float4 p3 = in4[i + 3 * stride];
        float4 r;
        r.x = interp_one(p0.x, sE, sSeg, sBkt);
        r.y = interp_one(p0.y, sE, sSeg, sBkt);
        r.z = interp_one(p0.z, sE, sSeg, sBkt);
        r.w = interp_one(p0.w, sE, sSeg, sBkt);
        nt_store4(&out4[i], r);
        r.x = interp_one(p1.x, sE, sSeg, sBkt);
        r.y = interp_one(p1.y, sE, sSeg, sBkt);
        r.z = interp_one(p1.z, sE, sSeg, sBkt);
        r.w = interp_one(p1.w, sE, sSeg, sBkt);
        nt_store4(&out4[i + stride], r);
        r.x = interp_one(p2.x, sE, sSeg, sBkt);
        r.y = interp_one(p2.y, sE, sSeg, sBkt);
        r.z = interp_one(p2.z, sE, sSeg, sBkt);
        r.w = interp_one(p2.w, sE, sSeg, sBkt);
        nt_store4(&out4[i + 2 * stride], r);
        r.x = interp_one(p3.x, sE, sSeg, sBkt);
        r.y = interp_one(p3.y, sE, sSeg, sBkt);
        r.z = interp_one(p3.z, sE, sSeg, sBkt);
        r.w = interp_one(p3.w, sE, sSeg, sBkt);
        nt_store4(&out4[i + 3 * stride], r);
    }
    for (; i < NP4; i += stride) {
        float4 p = in4[i];
        float4 r;
        r.x = interp_one(p.x, sE, sSeg, sBkt);
        r.y = interp_one(p.y, sE, sSeg, sBkt);
        r.z = interp_one(p.z, sE, sSeg, sBkt);
        r.w = interp_one(p.w, sE, sSeg, sBkt);
        nt_store4(&out4[i], r);
    }
}

extern "C" void kernel_launch(void* const* d_in, const int* in_sizes, int n_in,
                              void* d_out, int out_size, void* d_ws, size_t ws_size,
                              hipStream_t stream)
{
    const float* hdr = (const float*)d_in[0];  // [8,3,1080,1920]
    const float* w   = (const float*)d_in[1];  // [8,25]
    const float* E   = (const float*)d_in[2];  // [256] sorted
    const float* f0  = (const float*)d_in[3];  // [256]
    const float* Hb  = (const float*)d_in[4];  // [256,25]
    float* out = (float*)d_out;

    dim3 grid(256, 8, 1);   // 2048 blocks = 8 blocks/CU on 256 CUs, 32 waves/CU
    dim3 block(256, 1, 1);
    tmo_lut_kernel<<<grid, block, 0, stream>>>(hdr, w, E, f0, Hb, out);
}